// Round 1
// baseline (801.915 us; speedup 1.0000x reference)
//
#include <hip/hip_runtime.h>
#include <hip/hip_bf16.h>

#define D 128

// ---------------- graph preprocessing ----------------

__global__ void hist_kernel(const int* __restrict__ dst, int* __restrict__ cnt, int E) {
    int e = blockIdx.x * blockDim.x + threadIdx.x;
    if (e < E) atomicAdd(&cnt[dst[e]], 1);
}

__global__ void dinv_kernel(const int* __restrict__ cnt, float* __restrict__ dinv, int N) {
    int i = blockIdx.x * blockDim.x + threadIdx.x;
    if (i < N) dinv[i] = rsqrtf((float)(cnt[i] + 1));  // +1 self-loop; deg >= 1 always
}

// single-block exclusive scan over N counts -> row_start + fill_ptr
__global__ __launch_bounds__(1024) void scan_kernel(const int* __restrict__ cnt,
                                                    int* __restrict__ rs,
                                                    int* __restrict__ fp,
                                                    int N) {
    __shared__ int sums[1024];
    int t = threadIdx.x;
    int per = (N + 1023) / 1024;
    int base = t * per;
    int s = 0;
    for (int k = 0; k < per; ++k) {
        int idx = base + k;
        if (idx < N) s += cnt[idx];
    }
    sums[t] = s;
    __syncthreads();
    // Hillis-Steele inclusive scan
    for (int off = 1; off < 1024; off <<= 1) {
        int v = (t >= off) ? sums[t - off] : 0;
        __syncthreads();
        sums[t] += v;
        __syncthreads();
    }
    int run = sums[t] - s;  // exclusive prefix for this thread's chunk
    for (int k = 0; k < per; ++k) {
        int idx = base + k;
        if (idx < N) {
            rs[idx] = run;
            fp[idx] = run;
            run += cnt[idx];
        }
    }
    if (t == 1023) rs[N] = run;  // == E
}

__global__ void fill_kernel(const int* __restrict__ src, const int* __restrict__ dst,
                            int* __restrict__ fp, int* __restrict__ colv, int E) {
    int e = blockIdx.x * blockDim.x + threadIdx.x;
    if (e < E) {
        int slot = atomicAdd(&fp[dst[e]], 1);
        colv[slot] = src[e];
    }
}

// ---------------- GEMM: C[M,128] = A[M,128] @ W[128,128] (+bias) ----------------
// Block = 256 thr = 4 waves. Wave w: rowgroup = w>>1 (32 rows each), colhalf = w&1
// (64 cols, lane = col). A-row addresses are wave-uniform -> scalar loads (SGPR
// operand feeds v_fmac). C stores are coalesced (lane = contiguous col).
__global__ __launch_bounds__(256) void gemm128(const float* __restrict__ A,
                                               const float* __restrict__ W,
                                               const float* __restrict__ bias,
                                               float* __restrict__ C, int M) {
    int tid = threadIdx.x;
    int wave = __builtin_amdgcn_readfirstlane(tid >> 6);
    int lane = tid & 63;
    int rowg = wave >> 1;
    int colj = (wave & 1) * 64 + lane;
    int row0 = blockIdx.x * 64 + rowg * 32;

    float acc[32];
#pragma unroll
    for (int r = 0; r < 32; ++r) acc[r] = 0.f;

    bool full = (row0 + 32 <= M);

    for (int kc = 0; kc < 4; ++kc) {
        float wreg[32];
        const float* Wp = W + kc * 32 * D + colj;
#pragma unroll
        for (int kk = 0; kk < 32; ++kk) wreg[kk] = Wp[kk * D];

        if (full) {
#pragma unroll 8
            for (int r = 0; r < 32; ++r) {
                const float* a = A + (row0 + r) * D + kc * 32;
#pragma unroll
                for (int kk = 0; kk < 32; ++kk)
                    acc[r] = fmaf(a[kk], wreg[kk], acc[r]);
            }
        } else {
            for (int r = 0; r < 32; ++r) {
                if (row0 + r < M) {
                    const float* a = A + (row0 + r) * D + kc * 32;
#pragma unroll
                    for (int kk = 0; kk < 32; ++kk)
                        acc[r] = fmaf(a[kk], wreg[kk], acc[r]);
                }
            }
        }
    }

    float bv = bias ? bias[colj] : 0.f;
#pragma unroll
    for (int r = 0; r < 32; ++r) {
        int row = row0 + r;
        if (row < M) C[row * D + colj] = acc[r] + bv;
    }
}

// ---------------- aggregation: O[i] = dinv[i]*sum_j dinv[j]*T[j] + dinv[i]^2*T[i] + b ----------------
// One wave per node; lane holds float2 (2 features). Coalesced 512B row reads.
__global__ __launch_bounds__(256) void aggregate(const float* __restrict__ T,
                                                 const int* __restrict__ colv,
                                                 const int* __restrict__ rs,
                                                 const float* __restrict__ dinv,
                                                 const float* __restrict__ bias,
                                                 float* __restrict__ O,
                                                 int N, int do_relu) {
    int wave = __builtin_amdgcn_readfirstlane((int)(threadIdx.x >> 6));
    int lane = threadIdx.x & 63;
    int i = blockIdx.x * 4 + wave;
    if (i >= N) return;

    const float2* T2 = (const float2*)T;
    int f = lane;  // float2 index within row (row stride = 64 float2)

    int e0 = rs[i];
    int e1 = rs[i + 1];
    float ax = 0.f, ay = 0.f;

    int e = e0;
    for (; e + 4 <= e1; e += 4) {
        int j0 = colv[e], j1 = colv[e + 1], j2 = colv[e + 2], j3 = colv[e + 3];
        float w0 = dinv[j0], w1 = dinv[j1], w2 = dinv[j2], w3 = dinv[j3];
        float2 t0 = T2[j0 * 64 + f];
        float2 t1 = T2[j1 * 64 + f];
        float2 t2 = T2[j2 * 64 + f];
        float2 t3 = T2[j3 * 64 + f];
        ax += w0 * t0.x + w1 * t1.x + w2 * t2.x + w3 * t3.x;
        ay += w0 * t0.y + w1 * t1.y + w2 * t2.y + w3 * t3.y;
    }
    for (; e < e1; ++e) {
        int j = colv[e];
        float w = dinv[j];
        float2 t = T2[j * 64 + f];
        ax += w * t.x;
        ay += w * t.y;
    }

    float di = dinv[i];
    float d2 = di * di;
    float2 self = T2[i * 64 + f];
    float2 bv = ((const float2*)bias)[f];
    float rx = di * ax + d2 * self.x + bv.x;
    float ry = di * ay + d2 * self.y + bv.y;
    if (do_relu) {
        rx = fmaxf(rx, 0.f);
        ry = fmaxf(ry, 0.f);
    }
    float2 res;
    res.x = rx;
    res.y = ry;
    ((float2*)O)[i * 64 + f] = res;
}

// ---------------- launch ----------------

extern "C" void kernel_launch(void* const* d_in, const int* in_sizes, int n_in,
                              void* d_out, int out_size, void* d_ws, size_t ws_size,
                              hipStream_t stream) {
    const float* x   = (const float*)d_in[0];
    const int*   ei  = (const int*)d_in[1];
    const float* q   = (const float*)d_in[2];
    const float* W1  = (const float*)d_in[3];
    const float* b1  = (const float*)d_in[4];
    const float* W2  = (const float*)d_in[5];
    const float* b2  = (const float*)d_in[6];
    const float* Wq  = (const float*)d_in[7];
    const float* bq  = (const float*)d_in[8];

    int N  = in_sizes[0] / D;   // 50000
    int E  = in_sizes[1] / 2;   // 800000
    int MQ = in_sizes[2] / D;   // 20000

    const int* srcv = ei;
    const int* dstv = ei + E;

    // workspace carve (16B-aligned chunks)
    char* w = (char*)d_ws;
    float* bufA = (float*)w;            w += (size_t)N * D * 4;     // 25.6 MB
    int*   colv = (int*)w;              w += (size_t)E * 4;         // 3.2 MB
    int*   cnt  = (int*)w;              w += (size_t)N * 4;
    int*   rs   = (int*)w;              w += (size_t)(N + 4) * 4;
    int*   fp   = (int*)w;              w += (size_t)N * 4;
    float* dinv = (float*)w;            w += (size_t)N * 4;

    float* outq = (float*)d_out;            // ques [MQ,128]
    float* outh = outq + (size_t)MQ * D;    // h2   [N,128]
    float* bufB = outh;                     // h1 scratch lives in h2 region, overwritten later

    hipMemsetAsync(cnt, 0, (size_t)N * 4, stream);
    hist_kernel<<<(E + 255) / 256, 256, 0, stream>>>(dstv, cnt, E);
    dinv_kernel<<<(N + 255) / 256, 256, 0, stream>>>(cnt, dinv, N);
    scan_kernel<<<1, 1024, 0, stream>>>(cnt, rs, fp, N);
    fill_kernel<<<(E + 255) / 256, 256, 0, stream>>>(srcv, dstv, fp, colv, E);

    // conv1: t1 = x@W1 ; h1 = relu(agg(t1) + b1)
    gemm128<<<(N + 63) / 64, 256, 0, stream>>>(x, W1, nullptr, bufA, N);
    aggregate<<<(N + 3) / 4, 256, 0, stream>>>(bufA, colv, rs, dinv, b1, bufB, N, 1);

    // conv2: t2 = h1@W2 ; h2 = agg(t2) + b2
    gemm128<<<(N + 63) / 64, 256, 0, stream>>>(bufB, W2, nullptr, bufA, N);
    aggregate<<<(N + 3) / 4, 256, 0, stream>>>(bufA, colv, rs, dinv, b2, outh, N, 0);

    // ques = q@Wq + bq
    gemm128<<<(MQ + 63) / 64, 256, 0, stream>>>(q, Wq, bq, outq, MQ);
}

// Round 2
// 528.460 us; speedup vs baseline: 1.5175x; 1.5175x over previous
//
#include <hip/hip_runtime.h>

#define D 128

typedef __attribute__((ext_vector_type(8))) short bf16x8;
typedef __attribute__((ext_vector_type(4))) float f32x4;

__device__ __forceinline__ unsigned short f2b(float v) {
    unsigned u = __float_as_uint(v);
    unsigned r = u + 0x7fffu + ((u >> 16) & 1u);   // RNE, inputs never NaN
    return (unsigned short)(r >> 16);
}
__device__ __forceinline__ float b2f(unsigned short h) {
    return __uint_as_float(((unsigned)h) << 16);
}

// ---------------- graph preprocessing ----------------

__global__ void hist_kernel(const int* __restrict__ dst, int* __restrict__ cnt, int E) {
    int e = blockIdx.x * blockDim.x + threadIdx.x;
    if (e < E) atomicAdd(&cnt[dst[e]], 1);
}

__global__ void dinv_kernel(const int* __restrict__ cnt, float* __restrict__ dinv, int N) {
    int i = blockIdx.x * blockDim.x + threadIdx.x;
    if (i < N) dinv[i] = rsqrtf((float)(cnt[i] + 1));  // +1 self-loop
}

// single-block exclusive scan over N counts -> row_start + fill_ptr
__global__ __launch_bounds__(1024) void scan_kernel(const int* __restrict__ cnt,
                                                    int* __restrict__ rs,
                                                    int* __restrict__ fp,
                                                    int N) {
    __shared__ int sums[1024];
    int t = threadIdx.x;
    int per = (N + 1023) / 1024;
    int base = t * per;
    int s = 0;
    for (int k = 0; k < per; ++k) {
        int idx = base + k;
        if (idx < N) s += cnt[idx];
    }
    sums[t] = s;
    __syncthreads();
    for (int off = 1; off < 1024; off <<= 1) {
        int v = (t >= off) ? sums[t - off] : 0;
        __syncthreads();
        sums[t] += v;
        __syncthreads();
    }
    int run = sums[t] - s;
    for (int k = 0; k < per; ++k) {
        int idx = base + k;
        if (idx < N) {
            rs[idx] = run;
            fp[idx] = run;
            run += cnt[idx];
        }
    }
    if (t == 1023) rs[N] = run;
}

__global__ void fill_kernel(const int* __restrict__ src, const int* __restrict__ dst,
                            const float* __restrict__ dinv,
                            int* __restrict__ fp, int* __restrict__ colv,
                            float* __restrict__ colw, int E) {
    int e = blockIdx.x * blockDim.x + threadIdx.x;
    if (e < E) {
        int s = src[e];
        int slot = atomicAdd(&fp[dst[e]], 1);
        colv[slot] = s;
        colw[slot] = dinv[s];
    }
}

// ---------------- fp32 -> bf16 hi/lo split ----------------

__global__ void split4_kernel(const float4* __restrict__ X, ushort4* __restrict__ H,
                              ushort4* __restrict__ L, int n4) {
    int i = blockIdx.x * blockDim.x + threadIdx.x;
    if (i >= n4) return;
    float4 v = X[i];
    ushort4 h, l;
    h.x = f2b(v.x); l.x = f2b(v.x - b2f(h.x));
    h.y = f2b(v.y); l.y = f2b(v.y - b2f(h.y));
    h.z = f2b(v.z); l.z = f2b(v.z - b2f(h.z));
    h.w = f2b(v.w); l.w = f2b(v.w - b2f(h.w));
    H[i] = h;
    L[i] = l;
}

// W[128,128] fp32 -> Wt hi/lo bf16 [n][k] (transposed)
__global__ void wsplit_kernel(const float* __restrict__ W, unsigned short* __restrict__ Wth,
                              unsigned short* __restrict__ Wtl) {
    int t = blockIdx.x * blockDim.x + threadIdx.x;  // t = n*128 + k
    if (t >= D * D) return;
    int n = t >> 7, k = t & 127;
    float v = W[k * D + n];
    unsigned short h = f2b(v);
    Wth[t] = h;
    Wtl[t] = f2b(v - b2f(h));
}

// ---------------- MFMA GEMM: C[M,128] = (Ah+Al)[M,128] @ (Wh+Wl)[128,128] ----------------
// bf16 split, 3-term MFMA. No LDS: A-frags coalesced from row-major bf16,
// W-frags from L1/L2-hot 32KB Wt arrays. 4 waves/block, wave = 16 rows x 128 cols.
__global__ __launch_bounds__(256) void mfma_gemm(const unsigned short* __restrict__ Ah,
                                                 const unsigned short* __restrict__ Al,
                                                 const unsigned short* __restrict__ Wth,
                                                 const unsigned short* __restrict__ Wtl,
                                                 const float* __restrict__ bias,
                                                 float* __restrict__ C, int M) {
    int lane = threadIdx.x & 63;
    int wave = threadIdx.x >> 6;
    int m16 = (blockIdx.x * 4 + wave) * 16;  // 16-row tile base (M % 16 == 0)
    if (m16 >= M) return;
    int mrow = lane & 15;   // A: m index ; W: n index
    int quad = lane >> 4;   // k-quad

    f32x4 acc[8];
#pragma unroll
    for (int nt = 0; nt < 8; ++nt) acc[nt] = (f32x4){0.f, 0.f, 0.f, 0.f};

    const unsigned short* ah = Ah + (size_t)(m16 + mrow) * D + quad * 8;
    const unsigned short* al = Al + (size_t)(m16 + mrow) * D + quad * 8;

#pragma unroll
    for (int ks = 0; ks < 4; ++ks) {
        bf16x8 af = *(const bf16x8*)(ah + ks * 32);
        bf16x8 alf = *(const bf16x8*)(al + ks * 32);
#pragma unroll
        for (int nt = 0; nt < 8; ++nt) {
            const unsigned short* wp = Wth + (size_t)(nt * 16 + mrow) * D + ks * 32 + quad * 8;
            const unsigned short* wl = Wtl + (size_t)(nt * 16 + mrow) * D + ks * 32 + quad * 8;
            bf16x8 wf = *(const bf16x8*)wp;
            bf16x8 wlf = *(const bf16x8*)wl;
            acc[nt] = __builtin_amdgcn_mfma_f32_16x16x32_bf16(af, wf, acc[nt], 0, 0, 0);
            acc[nt] = __builtin_amdgcn_mfma_f32_16x16x32_bf16(af, wlf, acc[nt], 0, 0, 0);
            acc[nt] = __builtin_amdgcn_mfma_f32_16x16x32_bf16(alf, wf, acc[nt], 0, 0, 0);
        }
    }

    // C/D layout: col = lane&15, row = quad*4 + reg
#pragma unroll
    for (int nt = 0; nt < 8; ++nt) {
        int col = nt * 16 + mrow;
        float bv = bias ? bias[col] : 0.f;
#pragma unroll
        for (int r = 0; r < 4; ++r) {
            int row = m16 + quad * 4 + r;
            C[(size_t)row * D + col] = acc[nt][r] + bv;
        }
    }
}

// ---------------- aggregation ----------------
// O[i] = dinv[i] * sum_j w_j * T[j] + dinv[i]^2 * T[i] + b ; optional relu.
// mode 1: relu, write bf16 hi/lo (feeds next GEMM). mode 0: write fp32.
// Edge indices+weights prefetched 64-at-a-time into lane regs, broadcast via shfl.
__global__ __launch_bounds__(256) void aggregate(const float* __restrict__ T,
                                                 const int* __restrict__ colv,
                                                 const float* __restrict__ colw,
                                                 const int* __restrict__ rs,
                                                 const float* __restrict__ dinv,
                                                 const float* __restrict__ bias,
                                                 float* __restrict__ Of,
                                                 unsigned short* __restrict__ Oh,
                                                 unsigned short* __restrict__ Ol,
                                                 int N, int mode) {
    int wave = threadIdx.x >> 6;
    int lane = threadIdx.x & 63;
    int i = blockIdx.x * 4 + wave;
    if (i >= N) return;

    const float2* T2 = (const float2*)T;
    int f = lane;  // float2 index in row (row = 64 float2)

    int e0 = rs[i];
    int e1 = rs[i + 1];
    float ax = 0.f, ay = 0.f;

    for (int base = e0; base < e1; base += 64) {
        int cnt = e1 - base;
        if (cnt > 64) cnt = 64;
        int jv = (lane < cnt) ? colv[base + lane] : 0;
        float wv = (lane < cnt) ? colw[base + lane] : 0.f;

        int t = 0;
        for (; t + 4 <= cnt; t += 4) {
            int j0 = __shfl(jv, t), j1 = __shfl(jv, t + 1);
            int j2 = __shfl(jv, t + 2), j3 = __shfl(jv, t + 3);
            float w0 = __shfl(wv, t), w1 = __shfl(wv, t + 1);
            float w2 = __shfl(wv, t + 2), w3 = __shfl(wv, t + 3);
            float2 r0 = T2[(size_t)j0 * 64 + f];
            float2 r1 = T2[(size_t)j1 * 64 + f];
            float2 r2 = T2[(size_t)j2 * 64 + f];
            float2 r3 = T2[(size_t)j3 * 64 + f];
            ax += w0 * r0.x + w1 * r1.x + w2 * r2.x + w3 * r3.x;
            ay += w0 * r0.y + w1 * r1.y + w2 * r2.y + w3 * r3.y;
        }
        for (; t < cnt; ++t) {
            int j = __shfl(jv, t);
            float w = __shfl(wv, t);
            float2 r = T2[(size_t)j * 64 + f];
            ax += w * r.x;
            ay += w * r.y;
        }
    }

    float di = dinv[i];
    float2 self = T2[(size_t)i * 64 + f];
    float2 bv = ((const float2*)bias)[f];
    float rx = di * ax + di * di * self.x + bv.x;
    float ry = di * ay + di * di * self.y + bv.y;
    if (mode) {
        rx = fmaxf(rx, 0.f);
        ry = fmaxf(ry, 0.f);
        ushort2 h, l;
        h.x = f2b(rx); l.x = f2b(rx - b2f(h.x));
        h.y = f2b(ry); l.y = f2b(ry - b2f(h.y));
        ((ushort2*)Oh)[(size_t)i * 64 + f] = h;
        ((ushort2*)Ol)[(size_t)i * 64 + f] = l;
    } else {
        float2 res;
        res.x = rx;
        res.y = ry;
        ((float2*)Of)[(size_t)i * 64 + f] = res;
    }
}

// ---------------- launch ----------------

static inline char* carve(char*& w, size_t bytes) {
    char* p = w;
    w += (bytes + 255) & ~(size_t)255;
    return p;
}

extern "C" void kernel_launch(void* const* d_in, const int* in_sizes, int n_in,
                              void* d_out, int out_size, void* d_ws, size_t ws_size,
                              hipStream_t stream) {
    const float* x  = (const float*)d_in[0];
    const int*   ei = (const int*)d_in[1];
    const float* q  = (const float*)d_in[2];
    const float* W1 = (const float*)d_in[3];
    const float* b1 = (const float*)d_in[4];
    const float* W2 = (const float*)d_in[5];
    const float* b2 = (const float*)d_in[6];
    const float* Wq = (const float*)d_in[7];
    const float* bq = (const float*)d_in[8];

    int N  = in_sizes[0] / D;  // 50000
    int E  = in_sizes[1] / 2;  // 800000
    int MQ = in_sizes[2] / D;  // 20000

    const int* srcv = ei;
    const int* dstv = ei + E;

    char* w = (char*)d_ws;
    float*          bufA = (float*)carve(w, (size_t)N * D * 4);           // GEMM out / agg in
    unsigned short* Hb   = (unsigned short*)carve(w, (size_t)N * D * 2);  // bf16-hi (x -> h1 -> q)
    unsigned short* Lb   = (unsigned short*)carve(w, (size_t)N * D * 2);  // bf16-lo
    int*            colv = (int*)carve(w, (size_t)E * 4);
    float*          colw = (float*)carve(w, (size_t)E * 4);
    int*            cnt  = (int*)carve(w, (size_t)N * 4);
    int*            rs   = (int*)carve(w, (size_t)(N + 1) * 4);
    int*            fp   = (int*)carve(w, (size_t)N * 4);
    float*          dinv = (float*)carve(w, (size_t)N * 4);
    unsigned short* Wth1 = (unsigned short*)carve(w, D * D * 2);
    unsigned short* Wtl1 = (unsigned short*)carve(w, D * D * 2);
    unsigned short* Wth2 = (unsigned short*)carve(w, D * D * 2);
    unsigned short* Wtl2 = (unsigned short*)carve(w, D * D * 2);
    unsigned short* Wthq = (unsigned short*)carve(w, D * D * 2);
    unsigned short* Wtlq = (unsigned short*)carve(w, D * D * 2);

    float* outq = (float*)d_out;
    float* outh = outq + (size_t)MQ * D;

    // graph preprocessing
    hipMemsetAsync(cnt, 0, (size_t)N * 4, stream);
    hist_kernel<<<(E + 255) / 256, 256, 0, stream>>>(dstv, cnt, E);
    dinv_kernel<<<(N + 255) / 256, 256, 0, stream>>>(cnt, dinv, N);
    scan_kernel<<<1, 1024, 0, stream>>>(cnt, rs, fp, N);
    fill_kernel<<<(E + 255) / 256, 256, 0, stream>>>(srcv, dstv, dinv, fp, colv, colw, E);

    // weight conversions (tiny)
    wsplit_kernel<<<64, 256, 0, stream>>>(W1, Wth1, Wtl1);
    wsplit_kernel<<<64, 256, 0, stream>>>(W2, Wth2, Wtl2);
    wsplit_kernel<<<64, 256, 0, stream>>>(Wq, Wthq, Wtlq);

    // conv1: t1 = x@W1 ; h1 = relu(agg(t1)+b1) -> bf16 hi/lo
    int n4x = N * D / 4;
    split4_kernel<<<(n4x + 255) / 256, 256, 0, stream>>>((const float4*)x, (ushort4*)Hb, (ushort4*)Lb, n4x);
    mfma_gemm<<<(N + 63) / 64, 256, 0, stream>>>(Hb, Lb, Wth1, Wtl1, nullptr, bufA, N);
    aggregate<<<(N + 3) / 4, 256, 0, stream>>>(bufA, colv, colw, rs, dinv, b1, nullptr, Hb, Lb, N, 1);

    // conv2: t2 = h1@W2 ; h2 = agg(t2)+b2 -> fp32 out
    mfma_gemm<<<(N + 63) / 64, 256, 0, stream>>>(Hb, Lb, Wth2, Wtl2, nullptr, bufA, N);
    aggregate<<<(N + 3) / 4, 256, 0, stream>>>(bufA, colv, colw, rs, dinv, b2, outh, nullptr, nullptr, N, 0);

    // ques = q@Wq + bq
    int n4q = MQ * D / 4;
    split4_kernel<<<(n4q + 255) / 256, 256, 0, stream>>>((const float4*)q, (ushort4*)Hb, (ushort4*)Lb, n4q);
    mfma_gemm<<<(MQ + 63) / 64, 256, 0, stream>>>(Hb, Lb, Wthq, Wtlq, bq, outq, MQ);
}

// Round 3
// 407.720 us; speedup vs baseline: 1.9668x; 1.2961x over previous
//
#include <hip/hip_runtime.h>

#define D 128

typedef __attribute__((ext_vector_type(8))) short bf16x8;
typedef __attribute__((ext_vector_type(4))) float f32x4;

__device__ __forceinline__ unsigned short f2b(float v) {
    unsigned u = __float_as_uint(v);
    unsigned r = u + 0x7fffu + ((u >> 16) & 1u);   // RNE, inputs never NaN
    return (unsigned short)(r >> 16);
}
__device__ __forceinline__ float b2f(unsigned short h) {
    return __uint_as_float(((unsigned)h) << 16);
}

// ---------------- graph preprocessing ----------------

__global__ void hist_kernel(const int* __restrict__ dst, int* __restrict__ cnt, int E) {
    int e = blockIdx.x * blockDim.x + threadIdx.x;
    if (e < E) atomicAdd(&cnt[dst[e]], 1);
}

// ---- 3-phase multi-block exclusive scan over cnt[N] (chunk = 1024 elems/block) ----

__global__ __launch_bounds__(256) void scan_phase1(const int* __restrict__ cnt,
                                                   int* __restrict__ bsum, int N) {
    int t = threadIdx.x;
    int base = blockIdx.x * 1024 + t * 4;
    int s = 0;
    if (base + 4 <= N) {
        int4 v = *(const int4*)(cnt + base);
        s = v.x + v.y + v.z + v.w;
    } else {
        for (int k = 0; k < 4; ++k)
            if (base + k < N) s += cnt[base + k];
    }
    for (int off = 32; off; off >>= 1) s += __shfl_down(s, off);
    __shared__ int ws[4];
    if ((t & 63) == 0) ws[t >> 6] = s;
    __syncthreads();
    if (t == 0) bsum[blockIdx.x] = ws[0] + ws[1] + ws[2] + ws[3];
}

// single small block scans the (<=256) block sums; also writes rs[N] = E
__global__ __launch_bounds__(256) void scan_phase2(const int* __restrict__ bsum,
                                                   int* __restrict__ boff,
                                                   int* __restrict__ rs, int nb, int N) {
    __shared__ int sh[256];
    int t = threadIdx.x;
    int v = (t < nb) ? bsum[t] : 0;
    sh[t] = v;
    __syncthreads();
    for (int off = 1; off < 256; off <<= 1) {
        int o = (t >= off) ? sh[t - off] : 0;
        __syncthreads();
        sh[t] += o;
        __syncthreads();
    }
    if (t < nb) boff[t] = sh[t] - v;   // exclusive block offset
    if (t == 255) rs[N] = sh[255];     // total == E
}

// per-block rescan with offset; writes rs, fp, and dinv (cnt already in regs)
__global__ __launch_bounds__(256) void scan_phase3(const int* __restrict__ cnt,
                                                   const int* __restrict__ boff,
                                                   int* __restrict__ rs, int* __restrict__ fp,
                                                   float* __restrict__ dinv, int N) {
    __shared__ int tsum[256];
    int t = threadIdx.x;
    int base = blockIdx.x * 1024 + t * 4;
    int v[4];
    int s = 0;
    if (base + 4 <= N) {
        int4 vv = *(const int4*)(cnt + base);
        v[0] = vv.x; v[1] = vv.y; v[2] = vv.z; v[3] = vv.w;
        s = v[0] + v[1] + v[2] + v[3];
    } else {
        for (int k = 0; k < 4; ++k) {
            v[k] = (base + k < N) ? cnt[base + k] : 0;
            s += v[k];
        }
    }
    tsum[t] = s;
    __syncthreads();
    for (int off = 1; off < 256; off <<= 1) {
        int o = (t >= off) ? tsum[t - off] : 0;
        __syncthreads();
        tsum[t] += o;
        __syncthreads();
    }
    int run = boff[blockIdx.x] + tsum[t] - s;  // exclusive prefix of this thread's chunk
#pragma unroll
    for (int k = 0; k < 4; ++k) {
        int idx = base + k;
        if (idx < N) {
            rs[idx] = run;
            fp[idx] = run;
            dinv[idx] = rsqrtf((float)(v[k] + 1));  // +1 self-loop
            run += v[k];
        }
    }
}

__global__ void fill_kernel(const int* __restrict__ src, const int* __restrict__ dst,
                            const float* __restrict__ dinv,
                            int* __restrict__ fp, int* __restrict__ colv,
                            float* __restrict__ colw, int E) {
    int e = blockIdx.x * blockDim.x + threadIdx.x;
    if (e < E) {
        int s = src[e];
        int slot = atomicAdd(&fp[dst[e]], 1);
        colv[slot] = s;
        colw[slot] = dinv[s];
    }
}

// ---------------- fp32 -> bf16 hi/lo split ----------------

__global__ void split4_kernel(const float4* __restrict__ X, ushort4* __restrict__ H,
                              ushort4* __restrict__ L, int n4) {
    int i = blockIdx.x * blockDim.x + threadIdx.x;
    if (i >= n4) return;
    float4 v = X[i];
    ushort4 h, l;
    h.x = f2b(v.x); l.x = f2b(v.x - b2f(h.x));
    h.y = f2b(v.y); l.y = f2b(v.y - b2f(h.y));
    h.z = f2b(v.z); l.z = f2b(v.z - b2f(h.z));
    h.w = f2b(v.w); l.w = f2b(v.w - b2f(h.w));
    H[i] = h;
    L[i] = l;
}

// W[128,128] fp32 -> Wt hi/lo bf16 [n][k] (transposed)
__global__ void wsplit_kernel(const float* __restrict__ W, unsigned short* __restrict__ Wth,
                              unsigned short* __restrict__ Wtl) {
    int t = blockIdx.x * blockDim.x + threadIdx.x;  // t = n*128 + k
    if (t >= D * D) return;
    int n = t >> 7, k = t & 127;
    float v = W[k * D + n];
    unsigned short h = f2b(v);
    Wth[t] = h;
    Wtl[t] = f2b(v - b2f(h));
}

// ---------------- MFMA GEMM: C[M,128] = (Ah+Al)[M,128] @ (Wh+Wl)[128,128] ----------------
// bf16 split, 3-term MFMA. No LDS: A-frags coalesced from row-major bf16,
// W-frags from L1/L2-hot 32KB Wt arrays. 4 waves/block, wave = 16 rows x 128 cols.
__global__ __launch_bounds__(256) void mfma_gemm(const unsigned short* __restrict__ Ah,
                                                 const unsigned short* __restrict__ Al,
                                                 const unsigned short* __restrict__ Wth,
                                                 const unsigned short* __restrict__ Wtl,
                                                 const float* __restrict__ bias,
                                                 float* __restrict__ C, int M) {
    int lane = threadIdx.x & 63;
    int wave = threadIdx.x >> 6;
    int m16 = (blockIdx.x * 4 + wave) * 16;  // 16-row tile base (M % 16 == 0)
    if (m16 >= M) return;
    int mrow = lane & 15;   // A: m index ; W: n index
    int quad = lane >> 4;   // k-quad

    f32x4 acc[8];
#pragma unroll
    for (int nt = 0; nt < 8; ++nt) acc[nt] = (f32x4){0.f, 0.f, 0.f, 0.f};

    const unsigned short* ah = Ah + (size_t)(m16 + mrow) * D + quad * 8;
    const unsigned short* al = Al + (size_t)(m16 + mrow) * D + quad * 8;

#pragma unroll
    for (int ks = 0; ks < 4; ++ks) {
        bf16x8 af = *(const bf16x8*)(ah + ks * 32);
        bf16x8 alf = *(const bf16x8*)(al + ks * 32);
#pragma unroll
        for (int nt = 0; nt < 8; ++nt) {
            const unsigned short* wp = Wth + (size_t)(nt * 16 + mrow) * D + ks * 32 + quad * 8;
            const unsigned short* wl = Wtl + (size_t)(nt * 16 + mrow) * D + ks * 32 + quad * 8;
            bf16x8 wf = *(const bf16x8*)wp;
            bf16x8 wlf = *(const bf16x8*)wl;
            acc[nt] = __builtin_amdgcn_mfma_f32_16x16x32_bf16(af, wf, acc[nt], 0, 0, 0);
            acc[nt] = __builtin_amdgcn_mfma_f32_16x16x32_bf16(af, wlf, acc[nt], 0, 0, 0);
            acc[nt] = __builtin_amdgcn_mfma_f32_16x16x32_bf16(alf, wf, acc[nt], 0, 0, 0);
        }
    }

    // C/D layout: col = lane&15, row = quad*4 + reg
#pragma unroll
    for (int nt = 0; nt < 8; ++nt) {
        int col = nt * 16 + mrow;
        float bv = bias ? bias[col] : 0.f;
#pragma unroll
        for (int r = 0; r < 4; ++r) {
            int row = m16 + quad * 4 + r;
            C[(size_t)row * D + col] = acc[nt][r] + bv;
        }
    }
}

// ---------------- aggregation ----------------
// O[i] = dinv[i] * sum_j w_j * T[j] + dinv[i]^2 * T[i] + b ; optional relu.
// mode 1: relu, write bf16 hi/lo (feeds next GEMM). mode 0: write fp32.
// Edge indices+weights prefetched 64-at-a-time into lane regs, broadcast via shfl.
__global__ __launch_bounds__(256) void aggregate(const float* __restrict__ T,
                                                 const int* __restrict__ colv,
                                                 const float* __restrict__ colw,
                                                 const int* __restrict__ rs,
                                                 const float* __restrict__ dinv,
                                                 const float* __restrict__ bias,
                                                 float* __restrict__ Of,
                                                 unsigned short* __restrict__ Oh,
                                                 unsigned short* __restrict__ Ol,
                                                 int N, int mode) {
    int wave = threadIdx.x >> 6;
    int lane = threadIdx.x & 63;
    int i = blockIdx.x * 4 + wave;
    if (i >= N) return;

    const float2* T2 = (const float2*)T;
    int f = lane;  // float2 index in row (row = 64 float2)

    int e0 = rs[i];
    int e1 = rs[i + 1];
    float ax = 0.f, ay = 0.f;

    for (int base = e0; base < e1; base += 64) {
        int cnt = e1 - base;
        if (cnt > 64) cnt = 64;
        int jv = (lane < cnt) ? colv[base + lane] : 0;
        float wv = (lane < cnt) ? colw[base + lane] : 0.f;

        int t = 0;
        for (; t + 4 <= cnt; t += 4) {
            int j0 = __shfl(jv, t), j1 = __shfl(jv, t + 1);
            int j2 = __shfl(jv, t + 2), j3 = __shfl(jv, t + 3);
            float w0 = __shfl(wv, t), w1 = __shfl(wv, t + 1);
            float w2 = __shfl(wv, t + 2), w3 = __shfl(wv, t + 3);
            float2 r0 = T2[(size_t)j0 * 64 + f];
            float2 r1 = T2[(size_t)j1 * 64 + f];
            float2 r2 = T2[(size_t)j2 * 64 + f];
            float2 r3 = T2[(size_t)j3 * 64 + f];
            ax += w0 * r0.x + w1 * r1.x + w2 * r2.x + w3 * r3.x;
            ay += w0 * r0.y + w1 * r1.y + w2 * r2.y + w3 * r3.y;
        }
        for (; t < cnt; ++t) {
            int j = __shfl(jv, t);
            float w = __shfl(wv, t);
            float2 r = T2[(size_t)j * 64 + f];
            ax += w * r.x;
            ay += w * r.y;
        }
    }

    float di = dinv[i];
    float2 self = T2[(size_t)i * 64 + f];
    float2 bv = ((const float2*)bias)[f];
    float rx = di * ax + di * di * self.x + bv.x;
    float ry = di * ay + di * di * self.y + bv.y;
    if (mode) {
        rx = fmaxf(rx, 0.f);
        ry = fmaxf(ry, 0.f);
        ushort2 h, l;
        h.x = f2b(rx); l.x = f2b(rx - b2f(h.x));
        h.y = f2b(ry); l.y = f2b(ry - b2f(h.y));
        ((ushort2*)Oh)[(size_t)i * 64 + f] = h;
        ((ushort2*)Ol)[(size_t)i * 64 + f] = l;
    } else {
        float2 res;
        res.x = rx;
        res.y = ry;
        ((float2*)Of)[(size_t)i * 64 + f] = res;
    }
}

// ---------------- launch ----------------

static inline char* carve(char*& w, size_t bytes) {
    char* p = w;
    w += (bytes + 255) & ~(size_t)255;
    return p;
}

extern "C" void kernel_launch(void* const* d_in, const int* in_sizes, int n_in,
                              void* d_out, int out_size, void* d_ws, size_t ws_size,
                              hipStream_t stream) {
    const float* x  = (const float*)d_in[0];
    const int*   ei = (const int*)d_in[1];
    const float* q  = (const float*)d_in[2];
    const float* W1 = (const float*)d_in[3];
    const float* b1 = (const float*)d_in[4];
    const float* W2 = (const float*)d_in[5];
    const float* b2 = (const float*)d_in[6];
    const float* Wq = (const float*)d_in[7];
    const float* bq = (const float*)d_in[8];

    int N  = in_sizes[0] / D;  // 50000
    int E  = in_sizes[1] / 2;  // 800000
    int MQ = in_sizes[2] / D;  // 20000

    const int* srcv = ei;
    const int* dstv = ei + E;

    char* w = (char*)d_ws;
    float*          bufA = (float*)carve(w, (size_t)N * D * 4);           // GEMM out / agg in
    unsigned short* Hb   = (unsigned short*)carve(w, (size_t)N * D * 2);  // bf16-hi (x -> h1 -> q)
    unsigned short* Lb   = (unsigned short*)carve(w, (size_t)N * D * 2);  // bf16-lo
    int*            colv = (int*)carve(w, (size_t)E * 4);
    float*          colw = (float*)carve(w, (size_t)E * 4);
    int*            cnt  = (int*)carve(w, (size_t)N * 4);
    int*            rs   = (int*)carve(w, (size_t)(N + 1) * 4);
    int*            fp   = (int*)carve(w, (size_t)N * 4);
    float*          dinv = (float*)carve(w, (size_t)N * 4);
    int*            bsum = (int*)carve(w, 256 * 4);
    int*            boff = (int*)carve(w, 256 * 4);
    unsigned short* Wth1 = (unsigned short*)carve(w, D * D * 2);
    unsigned short* Wtl1 = (unsigned short*)carve(w, D * D * 2);
    unsigned short* Wth2 = (unsigned short*)carve(w, D * D * 2);
    unsigned short* Wtl2 = (unsigned short*)carve(w, D * D * 2);
    unsigned short* Wthq = (unsigned short*)carve(w, D * D * 2);
    unsigned short* Wtlq = (unsigned short*)carve(w, D * D * 2);

    float* outq = (float*)d_out;
    float* outh = outq + (size_t)MQ * D;

    int nb = (N + 1023) / 1024;  // scan blocks (49 for N=50000; must be <=256)

    // graph preprocessing
    hipMemsetAsync(cnt, 0, (size_t)N * 4, stream);
    hist_kernel<<<(E + 255) / 256, 256, 0, stream>>>(dstv, cnt, E);
    scan_phase1<<<nb, 256, 0, stream>>>(cnt, bsum, N);
    scan_phase2<<<1, 256, 0, stream>>>(bsum, boff, rs, nb, N);
    scan_phase3<<<nb, 256, 0, stream>>>(cnt, boff, rs, fp, dinv, N);
    fill_kernel<<<(E + 255) / 256, 256, 0, stream>>>(srcv, dstv, dinv, fp, colv, colw, E);

    // weight conversions (tiny)
    wsplit_kernel<<<64, 256, 0, stream>>>(W1, Wth1, Wtl1);
    wsplit_kernel<<<64, 256, 0, stream>>>(W2, Wth2, Wtl2);
    wsplit_kernel<<<64, 256, 0, stream>>>(Wq, Wthq, Wtlq);

    // conv1: t1 = x@W1 ; h1 = relu(agg(t1)+b1) -> bf16 hi/lo
    int n4x = N * D / 4;
    split4_kernel<<<(n4x + 255) / 256, 256, 0, stream>>>((const float4*)x, (ushort4*)Hb, (ushort4*)Lb, n4x);
    mfma_gemm<<<(N + 63) / 64, 256, 0, stream>>>(Hb, Lb, Wth1, Wtl1, nullptr, bufA, N);
    aggregate<<<(N + 3) / 4, 256, 0, stream>>>(bufA, colv, colw, rs, dinv, b1, nullptr, Hb, Lb, N, 1);

    // conv2: t2 = h1@W2 ; h2 = agg(t2)+b2 -> fp32 out
    mfma_gemm<<<(N + 63) / 64, 256, 0, stream>>>(Hb, Lb, Wth2, Wtl2, nullptr, bufA, N);
    aggregate<<<(N + 3) / 4, 256, 0, stream>>>(bufA, colv, colw, rs, dinv, b2, outh, nullptr, nullptr, N, 0);

    // ques = q@Wq + bq
    int n4q = MQ * D / 4;
    split4_kernel<<<(n4q + 255) / 256, 256, 0, stream>>>((const float4*)q, (ushort4*)Hb, (ushort4*)Lb, n4q);
    mfma_gemm<<<(MQ + 63) / 64, 256, 0, stream>>>(Hb, Lb, Wthq, Wtlq, bq, outq, MQ);
}